// Round 2
// baseline (152768.762 us; speedup 1.0000x reference)
//
#include <hip/hip_runtime.h>
#include <hip/hip_cooperative_groups.h>

#define T_STEPS 4096
#define N_RES   2048
#define N_IN    64
#define N_OUT   64
#define LEAK    0.3f
#define NOISE_S 0.01f

// ---------------------------------------------------------------------------
// Kernel 1: it[t][n] = dot(u[t,:], W_in[n,:]) + 0.01*noise[t][n]
// ---------------------------------------------------------------------------
__global__ __launch_bounds__(256) void input_terms_kernel(
    const float* __restrict__ u, const float* __restrict__ noise,
    const float* __restrict__ W_in, float* __restrict__ it) {
  const int t = blockIdx.x;
  const int tid = threadIdx.x;
  __shared__ float su[N_IN];
  if (tid < N_IN) su[tid] = u[(size_t)t * N_IN + tid];
  __syncthreads();
  #pragma unroll
  for (int k = 0; k < N_RES / 256; ++k) {
    const int n = tid + 256 * k;
    const float4* wr = reinterpret_cast<const float4*>(W_in + (size_t)n * N_IN);
    float acc = 0.f;
    #pragma unroll
    for (int j = 0; j < N_IN / 4; ++j) {
      float4 w4 = wr[j];
      acc = fmaf(w4.x, su[4 * j + 0], acc);
      acc = fmaf(w4.y, su[4 * j + 1], acc);
      acc = fmaf(w4.z, su[4 * j + 2], acc);
      acc = fmaf(w4.w, su[4 * j + 3], acc);
    }
    it[(size_t)t * N_RES + n] = acc + NOISE_S * noise[(size_t)t * N_RES + n];
  }
}

// ---------------------------------------------------------------------------
// Kernel 2: persistent recurrence with contention-free flag barrier.
// 256 WGs x 256 threads. WG w owns rows [8w, 8w+8); wave v rows 8w+2v(+1).
// Lane l holds W[row][l + 64*j] (j=0..31) pinned in VGPRs.
// Barrier: flags[wg] = t+1 (release, own slot — no RMW contention);
// thread tid of every WG polls flags[tid] >= t+1 (one parallel L3 round
// trip); __syncthreads joins. Monotonic flags + >= ⇒ ABA-safe; flags are
// zeroed per launch. One barrier/step is sufficient with double-buffered
// state: each WG reads sbuf[t&1] BEFORE setting its flag, and sbuf[t&1] is
// only overwritten (at step t+1) by WGs that already saw that flag.
// ---------------------------------------------------------------------------
__global__ __launch_bounds__(256, 1) void reservoir_kernel(
    const float* __restrict__ W, float* __restrict__ it, float* sbuf,
    unsigned int* flags) {
  const int wg = blockIdx.x;
  const int tid = threadIdx.x;
  const int wave = tid >> 6;
  const int lane = tid & 63;
  const int r0 = wg * 8 + wave * 2;  // this wave's two rows

  // Preload W rows into registers (16 MB read once), then pin them so the
  // compiler cannot sink the loads back into the loop (R0: VGPR=52 showed
  // it rematerialized these loads every step).
  float w0[32], w1[32];
  #pragma unroll
  for (int j = 0; j < 32; ++j) {
    w0[j] = W[(size_t)r0 * N_RES + lane + 64 * j];
    w1[j] = W[(size_t)(r0 + 1) * N_RES + lane + 64 * j];
  }
  #pragma unroll
  for (int j = 0; j < 32; ++j) {
    asm volatile("" : "+v"(w0[j]), "+v"(w1[j]));
  }

  __shared__ float ls[N_RES];

  for (unsigned int t = 0; t < T_STEPS; ++t) {
    const float* sr = sbuf + (t & 1) * N_RES;
    float* sw = sbuf + ((t + 1) & 1) * N_RES;

    // Prefetch this wave's input terms (own rows only — no cross-WG hazard).
    float itv = 0.f;
    if (lane < 2) itv = it[(size_t)t * N_RES + r0 + lane];

    // Stage state to LDS; agent-scope loads read through to the coherence
    // point (cross-XCD safe).
    #pragma unroll
    for (int k = 0; k < N_RES / 256; ++k) {
      const int idx = tid + 256 * k;
      ls[idx] = __hip_atomic_load(sr + idx, __ATOMIC_RELAXED,
                                  __HIP_MEMORY_SCOPE_AGENT);
    }
    __syncthreads();

    // Two dot products per wave.
    float a0 = 0.f, a1 = 0.f;
    #pragma unroll
    for (int j = 0; j < 32; ++j) {
      const float s = ls[lane + 64 * j];
      a0 = fmaf(w0[j], s, a0);
      a1 = fmaf(w1[j], s, a1);
    }
    #pragma unroll
    for (int off = 32; off > 0; off >>= 1) {
      a0 += __shfl_xor(a0, off);
      a1 += __shfl_xor(a1, off);
    }

    if (lane < 2) {
      const float a = lane ? a1 : a0;
      const float h = tanhf(itv + a);
      const float sold = ls[r0 + lane];
      const float snew = (1.0f - LEAK) * sold + LEAK * h;
      __hip_atomic_store(sw + r0 + lane, snew, __ATOMIC_RELEASE,
                         __HIP_MEMORY_SCOPE_AGENT);
      it[(size_t)t * N_RES + r0 + lane] = snew;  // record state for readout
    }

    // ---- custom barrier ----
    __syncthreads();  // every thread: own stores complete (vmcnt drained)
    if (tid == 0) {
      __threadfence();
      __hip_atomic_store(flags + wg, t + 1, __ATOMIC_RELEASE,
                         __HIP_MEMORY_SCOPE_AGENT);
    }
    while (__hip_atomic_load(flags + tid, __ATOMIC_RELAXED,
                             __HIP_MEMORY_SCOPE_AGENT) < t + 1) {
    }
    __syncthreads();
    __threadfence();  // acquire: order subsequent state loads
  }
}

// ---------------------------------------------------------------------------
// Kernel 3: out[t][o] = dot(states[t,:], rw[o,:]) + rb[o]
// ---------------------------------------------------------------------------
__global__ __launch_bounds__(256) void readout_kernel(
    const float* __restrict__ states, const float* __restrict__ rw,
    const float* __restrict__ rb, float* __restrict__ out) {
  const int t = blockIdx.x;
  const int tid = threadIdx.x;
  const int o = tid & 63;
  const int q = tid >> 6;  // 0..3
  __shared__ float ss[N_RES];
  #pragma unroll
  for (int k = 0; k < N_RES / 256; ++k)
    ss[tid + 256 * k] = states[(size_t)t * N_RES + tid + 256 * k];
  __syncthreads();

  const float4* r4 = reinterpret_cast<const float4*>(rw + (size_t)o * N_RES + q * 512);
  float acc = 0.f;
  #pragma unroll 8
  for (int j = 0; j < 128; ++j) {
    float4 w4 = r4[j];
    const int base = q * 512 + 4 * j;
    acc = fmaf(w4.x, ss[base + 0], acc);
    acc = fmaf(w4.y, ss[base + 1], acc);
    acc = fmaf(w4.z, ss[base + 2], acc);
    acc = fmaf(w4.w, ss[base + 3], acc);
  }
  __shared__ float red[256];
  red[tid] = acc;
  __syncthreads();
  if (tid < 64) {
    float v = red[tid] + red[tid + 64] + red[tid + 128] + red[tid + 192];
    out[(size_t)t * N_OUT + tid] = v + rb[tid];
  }
}

// ---------------------------------------------------------------------------
extern "C" void kernel_launch(void* const* d_in, const int* in_sizes, int n_in,
                              void* d_out, int out_size, void* d_ws, size_t ws_size,
                              hipStream_t stream) {
  const float* u     = (const float*)d_in[0];  // [4096, 64]
  const float* noise = (const float*)d_in[1];  // [4096, 2048]
  const float* W_in  = (const float*)d_in[2];  // [2048, 64]
  const float* W     = (const float*)d_in[3];  // [2048, 2048]
  const float* rw    = (const float*)d_in[4];  // [64, 2048]
  const float* rb    = (const float*)d_in[5];  // [64]
  float* out = (float*)d_out;                  // [4096, 64]

  float* it   = (float*)d_ws;  // 32 MB: input terms, overwritten with states
  float* sbuf = (float*)((char*)d_ws + (size_t)T_STEPS * N_RES * sizeof(float));
  unsigned int* flags = (unsigned int*)(sbuf + 2 * N_RES);

  // Zero state double-buffer AND barrier flags every call (ws is poisoned
  // once and never re-poisoned; flags must start at 0 for each replay).
  hipMemsetAsync(sbuf, 0, (2 * N_RES) * sizeof(float) + 256 * sizeof(unsigned int),
                 stream);

  input_terms_kernel<<<T_STEPS, 256, 0, stream>>>(u, noise, W_in, it);

  void* args[] = {(void*)&W, (void*)&it, (void*)&sbuf, (void*)&flags};
  hipLaunchCooperativeKernel((void*)reservoir_kernel, dim3(256), dim3(256),
                             args, 0, stream);

  readout_kernel<<<T_STEPS, 256, 0, stream>>>(it, rw, rb, out);
}

// Round 3
// 30274.469 us; speedup vs baseline: 5.0461x; 5.0461x over previous
//
#include <hip/hip_runtime.h>

#define T_STEPS 4096
#define N_RES   2048
#define N_IN    64
#define N_OUT   64
#define LEAK    0.3f
#define NOISE_S 0.01f

// ---------------------------------------------------------------------------
// Kernel 1: it[t][n] = dot(u[t,:], W_in[n,:]) + 0.01*noise[t][n]
// ---------------------------------------------------------------------------
__global__ __launch_bounds__(256) void input_terms_kernel(
    const float* __restrict__ u, const float* __restrict__ noise,
    const float* __restrict__ W_in, float* __restrict__ it) {
  const int t = blockIdx.x;
  const int tid = threadIdx.x;
  __shared__ float su[N_IN];
  if (tid < N_IN) su[tid] = u[(size_t)t * N_IN + tid];
  __syncthreads();
  #pragma unroll
  for (int k = 0; k < N_RES / 256; ++k) {
    const int n = tid + 256 * k;
    const float4* wr = reinterpret_cast<const float4*>(W_in + (size_t)n * N_IN);
    float acc = 0.f;
    #pragma unroll
    for (int j = 0; j < N_IN / 4; ++j) {
      float4 w4 = wr[j];
      acc = fmaf(w4.x, su[4 * j + 0], acc);
      acc = fmaf(w4.y, su[4 * j + 1], acc);
      acc = fmaf(w4.z, su[4 * j + 2], acc);
      acc = fmaf(w4.w, su[4 * j + 3], acc);
    }
    it[(size_t)t * N_RES + n] = acc + NOISE_S * noise[(size_t)t * N_RES + n];
  }
}

// ---------------------------------------------------------------------------
// Kernel 2: persistent recurrence. 256 WGs x 256 threads, 1 WG/CU.
// WG w owns rows [8w, 8w+8); W rows live in LDS (64 KB, loaded once).
// Per step: stage state (agent-scope loads, cache-bypass) to LDS, each wave
// computes 2 rows (float4 LDS reads, conflict-free), butterfly-reduce,
// tanh+leak on 2 lanes, agent-scope store to the other state buffer.
//
// Barrier (NO fences, NO RMW — avoids per-step L2 writeback/invalidate):
//   per-wave s_waitcnt vmcnt(0)  -> write-through stores ack'd at coherence pt
//   __syncthreads                -> all waves' stores drained
//   tid 0: flags[wg] = t+1       -> own slot, relaxed agent store
//   wave 0 only polls all 256 flags (4 coalesced loads) with s_sleep backoff
//   __syncthreads                -> whole WG proceeds
// Monotonic flags + >= compare: ABA-safe; flags zeroed each launch.
// One barrier/step is sufficient with the double-buffered state: a WG's
// reads of sbuf[t&1] complete (vmcnt) before its flag store, and sbuf[t&1]
// is only overwritten at t+1 by WGs that already observed that flag.
// ---------------------------------------------------------------------------
__global__ __launch_bounds__(256, 1) void reservoir_kernel(
    const float* __restrict__ W, float* __restrict__ it, float* sbuf,
    unsigned int* flags) {
  const int wg = blockIdx.x;
  const int tid = threadIdx.x;
  const int wave = tid >> 6;
  const int lane = tid & 63;
  const int R = wg * 8;            // WG's first row
  const int r0 = R + wave * 2;     // this wave's first row

  __shared__ float Wl[8 * N_RES];  // 64 KB
  __shared__ float ls[N_RES];      //  8 KB

  // Stage this WG's 8 W rows into LDS once (coalesced float4).
  {
    const float4* Wg = reinterpret_cast<const float4*>(W + (size_t)R * N_RES);
    float4* Wd = reinterpret_cast<float4*>(Wl);
    #pragma unroll
    for (int k = 0; k < 16; ++k) Wd[tid + 256 * k] = Wg[tid + 256 * k];
  }
  __syncthreads();

  const float4* S4 = reinterpret_cast<const float4*>(ls);
  const float4* W0 = reinterpret_cast<const float4*>(Wl + (size_t)(2 * wave) * N_RES);
  const float4* W1 = reinterpret_cast<const float4*>(Wl + (size_t)(2 * wave + 1) * N_RES);

  for (unsigned int t = 0; t < T_STEPS; ++t) {
    const float* sr = sbuf + (t & 1) * N_RES;
    float* sw = sbuf + ((t + 1) & 1) * N_RES;

    // Prefetch this wave's input term (own rows — no cross-WG hazard).
    float itv = 0.f;
    if (lane < 2) itv = it[(size_t)t * N_RES + r0 + lane];

    // Stage state to LDS; agent-scope loads bypass stale L1/L2 (cross-XCD).
    #pragma unroll
    for (int k = 0; k < N_RES / 256; ++k) {
      const int idx = tid + 256 * k;
      ls[idx] = __hip_atomic_load(sr + idx, __ATOMIC_RELAXED,
                                  __HIP_MEMORY_SCOPE_AGENT);
    }
    __syncthreads();

    // Two dot products per wave (conflict-free float4 LDS reads).
    float a0 = 0.f, a1 = 0.f;
    #pragma unroll
    for (int j = 0; j < 8; ++j) {
      const float4 s4 = S4[lane + 64 * j];
      const float4 x0 = W0[lane + 64 * j];
      const float4 x1 = W1[lane + 64 * j];
      a0 = fmaf(x0.x, s4.x, a0); a0 = fmaf(x0.y, s4.y, a0);
      a0 = fmaf(x0.z, s4.z, a0); a0 = fmaf(x0.w, s4.w, a0);
      a1 = fmaf(x1.x, s4.x, a1); a1 = fmaf(x1.y, s4.y, a1);
      a1 = fmaf(x1.z, s4.z, a1); a1 = fmaf(x1.w, s4.w, a1);
    }
    #pragma unroll
    for (int off = 32; off > 0; off >>= 1) {
      a0 += __shfl_xor(a0, off);
      a1 += __shfl_xor(a1, off);
    }

    if (lane < 2) {
      const float a = lane ? a1 : a0;
      const float h = tanhf(itv + a);
      const float sold = ls[r0 + lane];
      const float snew = (1.0f - LEAK) * sold + LEAK * h;
      __hip_atomic_store(sw + r0 + lane, snew, __ATOMIC_RELAXED,
                         __HIP_MEMORY_SCOPE_AGENT);
      it[(size_t)t * N_RES + r0 + lane] = snew;  // record state for readout
    }
    // This wave's write-through stores ack'd at the coherence point.
    asm volatile("s_waitcnt vmcnt(0)" ::: "memory");
    __syncthreads();  // all 4 waves drained

    // Arrival: own-slot relaxed store (no RMW, no fence).
    if (tid == 0) {
      __hip_atomic_store(flags + wg, t + 1, __ATOMIC_RELAXED,
                         __HIP_MEMORY_SCOPE_AGENT);
    }
    // Wait: only wave 0 polls (cuts spin traffic 4x), with backoff.
    if (wave == 0) {
      const unsigned int tgt = t + 1;
      for (;;) {
        const unsigned int f0 = __hip_atomic_load(flags + lane, __ATOMIC_RELAXED,
                                                  __HIP_MEMORY_SCOPE_AGENT);
        const unsigned int f1 = __hip_atomic_load(flags + 64 + lane, __ATOMIC_RELAXED,
                                                  __HIP_MEMORY_SCOPE_AGENT);
        const unsigned int f2 = __hip_atomic_load(flags + 128 + lane, __ATOMIC_RELAXED,
                                                  __HIP_MEMORY_SCOPE_AGENT);
        const unsigned int f3 = __hip_atomic_load(flags + 192 + lane, __ATOMIC_RELAXED,
                                                  __HIP_MEMORY_SCOPE_AGENT);
        const bool ok = (f0 >= tgt) & (f1 >= tgt) & (f2 >= tgt) & (f3 >= tgt);
        if (__all(ok)) break;
        __builtin_amdgcn_s_sleep(2);
      }
    }
    __syncthreads();  // join; next step's loads are agent-scope (no stale data)
  }
}

// ---------------------------------------------------------------------------
// Kernel 3: out[t][o] = dot(states[t,:], rw[o,:]) + rb[o]
// ---------------------------------------------------------------------------
__global__ __launch_bounds__(256) void readout_kernel(
    const float* __restrict__ states, const float* __restrict__ rw,
    const float* __restrict__ rb, float* __restrict__ out) {
  const int t = blockIdx.x;
  const int tid = threadIdx.x;
  const int o = tid & 63;
  const int q = tid >> 6;  // 0..3
  __shared__ float ss[N_RES];
  #pragma unroll
  for (int k = 0; k < N_RES / 256; ++k)
    ss[tid + 256 * k] = states[(size_t)t * N_RES + tid + 256 * k];
  __syncthreads();

  const float4* r4 = reinterpret_cast<const float4*>(rw + (size_t)o * N_RES + q * 512);
  float acc = 0.f;
  #pragma unroll 8
  for (int j = 0; j < 128; ++j) {
    float4 w4 = r4[j];
    const int base = q * 512 + 4 * j;
    acc = fmaf(w4.x, ss[base + 0], acc);
    acc = fmaf(w4.y, ss[base + 1], acc);
    acc = fmaf(w4.z, ss[base + 2], acc);
    acc = fmaf(w4.w, ss[base + 3], acc);
  }
  __shared__ float red[256];
  red[tid] = acc;
  __syncthreads();
  if (tid < 64) {
    float v = red[tid] + red[tid + 64] + red[tid + 128] + red[tid + 192];
    out[(size_t)t * N_OUT + tid] = v + rb[tid];
  }
}

// ---------------------------------------------------------------------------
extern "C" void kernel_launch(void* const* d_in, const int* in_sizes, int n_in,
                              void* d_out, int out_size, void* d_ws, size_t ws_size,
                              hipStream_t stream) {
  const float* u     = (const float*)d_in[0];  // [4096, 64]
  const float* noise = (const float*)d_in[1];  // [4096, 2048]
  const float* W_in  = (const float*)d_in[2];  // [2048, 64]
  const float* W     = (const float*)d_in[3];  // [2048, 2048]
  const float* rw    = (const float*)d_in[4];  // [64, 2048]
  const float* rb    = (const float*)d_in[5];  // [64]
  float* out = (float*)d_out;                  // [4096, 64]

  float* it   = (float*)d_ws;  // 32 MB: input terms, overwritten with states
  float* sbuf = (float*)((char*)d_ws + (size_t)T_STEPS * N_RES * sizeof(float));
  unsigned int* flags = (unsigned int*)(sbuf + 2 * N_RES);

  // Zero state double-buffer AND flags every call (ws is not re-poisoned
  // between replays; both end a run non-zero).
  hipMemsetAsync(sbuf, 0,
                 (2 * N_RES) * sizeof(float) + 256 * sizeof(unsigned int),
                 stream);

  input_terms_kernel<<<T_STEPS, 256, 0, stream>>>(u, noise, W_in, it);

  void* args[] = {(void*)&W, (void*)&it, (void*)&sbuf, (void*)&flags};
  hipLaunchCooperativeKernel((void*)reservoir_kernel, dim3(256), dim3(256),
                             args, 0, stream);

  readout_kernel<<<T_STEPS, 256, 0, stream>>>(it, rw, rb, out);
}

// Round 4
// 15441.336 us; speedup vs baseline: 9.8935x; 1.9606x over previous
//
#include <hip/hip_runtime.h>

#define T_STEPS 4096
#define N_RES   2048
#define N_IN    64
#define N_OUT   64
#define LEAK    0.3f
#define NOISE_S 0.01f

// ---------------------------------------------------------------------------
// Kernel 1: it[t][n] = dot(u[t,:], W_in[n,:]) + 0.01*noise[t][n]
// ---------------------------------------------------------------------------
__global__ __launch_bounds__(256) void input_terms_kernel(
    const float* __restrict__ u, const float* __restrict__ noise,
    const float* __restrict__ W_in, float* __restrict__ it) {
  const int t = blockIdx.x;
  const int tid = threadIdx.x;
  __shared__ float su[N_IN];
  if (tid < N_IN) su[tid] = u[(size_t)t * N_IN + tid];
  __syncthreads();
  #pragma unroll
  for (int k = 0; k < N_RES / 256; ++k) {
    const int n = tid + 256 * k;
    const float4* wr = reinterpret_cast<const float4*>(W_in + (size_t)n * N_IN);
    float acc = 0.f;
    #pragma unroll
    for (int j = 0; j < N_IN / 4; ++j) {
      float4 w4 = wr[j];
      acc = fmaf(w4.x, su[4 * j + 0], acc);
      acc = fmaf(w4.y, su[4 * j + 1], acc);
      acc = fmaf(w4.z, su[4 * j + 2], acc);
      acc = fmaf(w4.w, su[4 * j + 3], acc);
    }
    it[(size_t)t * N_RES + n] = acc + NOISE_S * noise[(size_t)t * N_RES + n];
  }
}

// ---------------------------------------------------------------------------
// Kernel 2: persistent recurrence with SELF-ANNOUNCING TAGGED STATE.
// 256 WGs x 256 threads, 1 WG/CU. WG w owns rows [8w, 8w+8); W in LDS.
//
// State entry = 8B word: high32 = step tag, low32 = float bits. Producer
// emits ONE relaxed agent-scope 8B store — that store is simultaneously the
// data transfer AND the barrier arrival. Consumers poll the entries they
// need until tag >= t; the polled word already contains the value (no
// separate state load, no flag array, no vmcnt ack, no fences).
//
// Race-freedom (double buffer + tags): an entry of buf[b] advances t -> t+2
// only after its producer consumed ALL of s_{t+1}; s_{t+1} complete implies
// every WG finished reading s_t. So a consumer polling for tag t can only
// observe {t-2, t} — never a too-new value. Tags are monotonic; buffers are
// zeroed each launch (tag 0 = initial zero state, matching reset_state).
// ---------------------------------------------------------------------------
__global__ __launch_bounds__(256, 1) void reservoir_kernel(
    const float* __restrict__ W, float* __restrict__ it,
    unsigned long long* sb64) {
  const int wg = blockIdx.x;
  const int tid = threadIdx.x;
  const int wave = tid >> 6;
  const int lane = tid & 63;
  const int R = wg * 8;            // WG's first row
  const int r0 = R + wave * 2;     // this wave's first row

  __shared__ float Wl[8 * N_RES];  // 64 KB
  __shared__ float ls[N_RES];      //  8 KB

  // Stage this WG's 8 W rows into LDS once (coalesced float4).
  {
    const float4* Wg = reinterpret_cast<const float4*>(W + (size_t)R * N_RES);
    float4* Wd = reinterpret_cast<float4*>(Wl);
    #pragma unroll
    for (int k = 0; k < 16; ++k) Wd[tid + 256 * k] = Wg[tid + 256 * k];
  }
  __syncthreads();

  const float4* S4 = reinterpret_cast<const float4*>(ls);
  const float4* W0 = reinterpret_cast<const float4*>(Wl + (size_t)(2 * wave) * N_RES);
  const float4* W1 = reinterpret_cast<const float4*>(Wl + (size_t)(2 * wave + 1) * N_RES);

  for (unsigned int t = 0; t < T_STEPS; ++t) {
    const unsigned long long* srb = sb64 + (t & 1) * N_RES;        // s_t
    unsigned long long* swb = sb64 + ((t + 1) & 1) * N_RES;        // s_{t+1}

    // Prefetch this wave's input term (own rows — no cross-WG hazard).
    float itv = 0.f;
    if (lane < 2) itv = it[(size_t)t * N_RES + r0 + lane];

    // Poll s_t directly: thread tid owns entries tid + 256k (coalesced
    // 512B per wave). The load that sees the tag also delivers the value.
    {
      unsigned int pend = 0xFFu;
      while (pend) {
        #pragma unroll
        for (int k = 0; k < 8; ++k) {
          if (pend & (1u << k)) {
            const unsigned long long p = __hip_atomic_load(
                srb + tid + 256 * k, __ATOMIC_RELAXED, __HIP_MEMORY_SCOPE_AGENT);
            if ((unsigned int)(p >> 32) >= t) {
              ls[tid + 256 * k] = __uint_as_float((unsigned int)p);
              pend &= ~(1u << k);
            }
          }
        }
        if (pend) __builtin_amdgcn_s_sleep(1);
      }
    }
    __syncthreads();  // ls fully populated

    // Two dot products per wave (conflict-free float4 LDS reads).
    float a0 = 0.f, a1 = 0.f;
    #pragma unroll
    for (int j = 0; j < 8; ++j) {
      const float4 s4 = S4[lane + 64 * j];
      const float4 x0 = W0[lane + 64 * j];
      const float4 x1 = W1[lane + 64 * j];
      a0 = fmaf(x0.x, s4.x, a0); a0 = fmaf(x0.y, s4.y, a0);
      a0 = fmaf(x0.z, s4.z, a0); a0 = fmaf(x0.w, s4.w, a0);
      a1 = fmaf(x1.x, s4.x, a1); a1 = fmaf(x1.y, s4.y, a1);
      a1 = fmaf(x1.z, s4.z, a1); a1 = fmaf(x1.w, s4.w, a1);
    }
    #pragma unroll
    for (int off = 32; off > 0; off >>= 1) {
      a0 += __shfl_xor(a0, off);
      a1 += __shfl_xor(a1, off);
    }

    if (lane < 2) {
      const float a = lane ? a1 : a0;
      const float h = tanhf(itv + a);
      const float sold = ls[r0 + lane];
      const float snew = (1.0f - LEAK) * sold + LEAK * h;
      const unsigned long long pk =
          ((unsigned long long)(t + 1) << 32) | (unsigned long long)__float_as_uint(snew);
      // Single 8B store: data + arrival in one shot (fire-and-forget).
      __hip_atomic_store(swb + r0 + lane, pk, __ATOMIC_RELAXED,
                         __HIP_MEMORY_SCOPE_AGENT);
      it[(size_t)t * N_RES + r0 + lane] = snew;  // record state for readout
    }

    __syncthreads();  // WAR: all waves done reading ls before next poll fills it
  }
}

// ---------------------------------------------------------------------------
// Kernel 3: out[t][o] = dot(states[t,:], rw[o,:]) + rb[o]
// ---------------------------------------------------------------------------
__global__ __launch_bounds__(256) void readout_kernel(
    const float* __restrict__ states, const float* __restrict__ rw,
    const float* __restrict__ rb, float* __restrict__ out) {
  const int t = blockIdx.x;
  const int tid = threadIdx.x;
  const int o = tid & 63;
  const int q = tid >> 6;  // 0..3
  __shared__ float ss[N_RES];
  #pragma unroll
  for (int k = 0; k < N_RES / 256; ++k)
    ss[tid + 256 * k] = states[(size_t)t * N_RES + tid + 256 * k];
  __syncthreads();

  const float4* r4 = reinterpret_cast<const float4*>(rw + (size_t)o * N_RES + q * 512);
  float acc = 0.f;
  #pragma unroll 8
  for (int j = 0; j < 128; ++j) {
    float4 w4 = r4[j];
    const int base = q * 512 + 4 * j;
    acc = fmaf(w4.x, ss[base + 0], acc);
    acc = fmaf(w4.y, ss[base + 1], acc);
    acc = fmaf(w4.z, ss[base + 2], acc);
    acc = fmaf(w4.w, ss[base + 3], acc);
  }
  __shared__ float red[256];
  red[tid] = acc;
  __syncthreads();
  if (tid < 64) {
    float v = red[tid] + red[tid + 64] + red[tid + 128] + red[tid + 192];
    out[(size_t)t * N_OUT + tid] = v + rb[tid];
  }
}

// ---------------------------------------------------------------------------
extern "C" void kernel_launch(void* const* d_in, const int* in_sizes, int n_in,
                              void* d_out, int out_size, void* d_ws, size_t ws_size,
                              hipStream_t stream) {
  const float* u     = (const float*)d_in[0];  // [4096, 64]
  const float* noise = (const float*)d_in[1];  // [4096, 2048]
  const float* W_in  = (const float*)d_in[2];  // [2048, 64]
  const float* W     = (const float*)d_in[3];  // [2048, 2048]
  const float* rw    = (const float*)d_in[4];  // [64, 2048]
  const float* rb    = (const float*)d_in[5];  // [64]
  float* out = (float*)d_out;                  // [4096, 64]

  float* it = (float*)d_ws;  // 32 MB: input terms, overwritten with states
  unsigned long long* sb64 =
      (unsigned long long*)((char*)d_ws + (size_t)T_STEPS * N_RES * sizeof(float));

  // Zero both tagged state buffers every call (tags monotonic per launch;
  // ws is not re-poisoned between replays). 2 * 2048 * 8B = 32 KB.
  hipMemsetAsync(sb64, 0, 2 * N_RES * sizeof(unsigned long long), stream);

  input_terms_kernel<<<T_STEPS, 256, 0, stream>>>(u, noise, W_in, it);

  void* args[] = {(void*)&W, (void*)&it, (void*)&sb64};
  hipLaunchCooperativeKernel((void*)reservoir_kernel, dim3(256), dim3(256),
                             args, 0, stream);

  readout_kernel<<<T_STEPS, 256, 0, stream>>>(it, rw, rb, out);
}

// Round 5
// 11536.729 us; speedup vs baseline: 13.2419x; 1.3385x over previous
//
#include <hip/hip_runtime.h>

#define T_STEPS 4096
#define N_RES   2048
#define N_IN    64
#define N_OUT   64
#define LEAK    0.3f
#define NOISE_S 0.01f

typedef unsigned int uint32x4 __attribute__((ext_vector_type(4)));

// ---------------------------------------------------------------------------
// Kernel 1: it[t][n] = dot(u[t,:], W_in[n,:]) + 0.01*noise[t][n]
// ---------------------------------------------------------------------------
__global__ __launch_bounds__(256) void input_terms_kernel(
    const float* __restrict__ u, const float* __restrict__ noise,
    const float* __restrict__ W_in, float* __restrict__ it) {
  const int t = blockIdx.x;
  const int tid = threadIdx.x;
  __shared__ float su[N_IN];
  if (tid < N_IN) su[tid] = u[(size_t)t * N_IN + tid];
  __syncthreads();
  #pragma unroll
  for (int k = 0; k < N_RES / 256; ++k) {
    const int n = tid + 256 * k;
    const float4* wr = reinterpret_cast<const float4*>(W_in + (size_t)n * N_IN);
    float acc = 0.f;
    #pragma unroll
    for (int j = 0; j < N_IN / 4; ++j) {
      float4 w4 = wr[j];
      acc = fmaf(w4.x, su[4 * j + 0], acc);
      acc = fmaf(w4.y, su[4 * j + 1], acc);
      acc = fmaf(w4.z, su[4 * j + 2], acc);
      acc = fmaf(w4.w, su[4 * j + 3], acc);
    }
    it[(size_t)t * N_RES + n] = acc + NOISE_S * noise[(size_t)t * N_RES + n];
  }
}

// ---------------------------------------------------------------------------
// Kernel 2: persistent recurrence, 4B self-announcing tagged state.
//
// State word = fp32 bits with the low 2 mantissa bits replaced by (step&3).
// Buffer skew between WGs is provably <= 2 steps (a producer advances a slot
// t -> t+2 only after every WG consumed s_{t+1}), so mod-4 tags distinguish
// fresh (t&3) from stale ((t-2)&3). Value perturbation <= 3 ulp — negligible.
//
// Poll: thread tid owns entries [4*tid, 4*tid+4) and [1024+4*tid, ...): two
// global_load_dwordx4 (sc0 sc1 = read at coherence point) per sweep, issued
// back-to-back under one vmcnt. Producer: the WG's 8 new values are gathered
// in LDS and written as two packed dwordx4 stores (sc0 sc1 write-through) —
// 2 packets instead of 8, and poll groups flip whole.
// ---------------------------------------------------------------------------
__global__ __launch_bounds__(256, 1) void reservoir_kernel(
    const float* __restrict__ W, float* __restrict__ it,
    unsigned int* sbuf) {
  const int wg = blockIdx.x;
  const int tid = threadIdx.x;
  const int wave = tid >> 6;
  const int lane = tid & 63;
  const int R = wg * 8;            // WG's first row
  const int r0 = R + wave * 2;     // this wave's first row

  __shared__ float Wl[8 * N_RES];  // 64 KB
  __shared__ float ls[N_RES];      //  8 KB
  __shared__ float stg[8];         // gather of this WG's 8 new state values

  // Stage this WG's 8 W rows into LDS once (coalesced float4).
  {
    const float4* Wg = reinterpret_cast<const float4*>(W + (size_t)R * N_RES);
    float4* Wd = reinterpret_cast<float4*>(Wl);
    #pragma unroll
    for (int k = 0; k < 16; ++k) Wd[tid + 256 * k] = Wg[tid + 256 * k];
  }
  __syncthreads();

  const float4* S4 = reinterpret_cast<const float4*>(ls);
  const float4* W0 = reinterpret_cast<const float4*>(Wl + (size_t)(2 * wave) * N_RES);
  const float4* W1 = reinterpret_cast<const float4*>(Wl + (size_t)(2 * wave + 1) * N_RES);
  uint32x4* lsv = reinterpret_cast<uint32x4*>(ls);

  for (unsigned int t = 0; t < T_STEPS; ++t) {
    const unsigned int* srb = sbuf + (t & 1) * N_RES;        // s_t
    unsigned int* swb = sbuf + ((t + 1) & 1) * N_RES;        // s_{t+1}
    const unsigned int tag = t & 3u;

    // Prefetch this wave's input term (own rows; overlaps with the poll).
    float itv = 0.f;
    if (lane < 2) itv = it[(size_t)t * N_RES + r0 + lane];

    // ---- poll s_t (self-announcing words) ----
    {
      const uint32x4* pa = reinterpret_cast<const uint32x4*>(srb) + tid;
      const uint32x4* pb = pa + 256;
      unsigned int need = 3u;
      for (;;) {
        uint32x4 va, vb;
        if (need == 3u) {
          asm volatile(
              "global_load_dwordx4 %0, %2, off sc0 sc1\n\t"
              "global_load_dwordx4 %1, %3, off sc0 sc1\n\t"
              "s_waitcnt vmcnt(0)"
              : "=&v"(va), "=&v"(vb)
              : "v"(pa), "v"(pb)
              : "memory");
          if ((((va[0] ^ tag) | (va[1] ^ tag) | (va[2] ^ tag) | (va[3] ^ tag)) & 3u) == 0u) {
            lsv[tid] = va;
            need &= ~1u;
          }
          if ((((vb[0] ^ tag) | (vb[1] ^ tag) | (vb[2] ^ tag) | (vb[3] ^ tag)) & 3u) == 0u) {
            lsv[256 + tid] = vb;
            need &= ~2u;
          }
        } else if (need == 1u) {
          asm volatile(
              "global_load_dwordx4 %0, %1, off sc0 sc1\n\t"
              "s_waitcnt vmcnt(0)"
              : "=&v"(va) : "v"(pa) : "memory");
          if ((((va[0] ^ tag) | (va[1] ^ tag) | (va[2] ^ tag) | (va[3] ^ tag)) & 3u) == 0u) {
            lsv[tid] = va;
            need = 0u;
          }
        } else {
          asm volatile(
              "global_load_dwordx4 %0, %1, off sc0 sc1\n\t"
              "s_waitcnt vmcnt(0)"
              : "=&v"(vb) : "v"(pb) : "memory");
          if ((((vb[0] ^ tag) | (vb[1] ^ tag) | (vb[2] ^ tag) | (vb[3] ^ tag)) & 3u) == 0u) {
            lsv[256 + tid] = vb;
            need = 0u;
          }
        }
        if (!need) break;
        __builtin_amdgcn_s_sleep(1);
      }
    }
    __syncthreads();  // ls fully populated

    // ---- two dot products per wave (conflict-free float4 LDS reads) ----
    float a0 = 0.f, a1 = 0.f;
    #pragma unroll
    for (int j = 0; j < 8; ++j) {
      const float4 s4 = S4[lane + 64 * j];
      const float4 x0 = W0[lane + 64 * j];
      const float4 x1 = W1[lane + 64 * j];
      a0 = fmaf(x0.x, s4.x, a0); a0 = fmaf(x0.y, s4.y, a0);
      a0 = fmaf(x0.z, s4.z, a0); a0 = fmaf(x0.w, s4.w, a0);
      a1 = fmaf(x1.x, s4.x, a1); a1 = fmaf(x1.y, s4.y, a1);
      a1 = fmaf(x1.z, s4.z, a1); a1 = fmaf(x1.w, s4.w, a1);
    }
    #pragma unroll
    for (int off = 32; off > 0; off >>= 1) {
      a0 += __shfl_xor(a0, off);
      a1 += __shfl_xor(a1, off);
    }

    if (lane < 2) {
      const float a = lane ? a1 : a0;
      const float h = tanhf(itv + a);
      const float sold = ls[r0 + lane];
      const float snew = (1.0f - LEAK) * sold + LEAK * h;
      stg[wave * 2 + lane] = snew;                 // gather for packed store
      it[(size_t)t * N_RES + r0 + lane] = snew;    // record state for readout
    }
    __syncthreads();  // stg complete; also guards ls WAR vs next poll

    // ---- packed broadcast: 2 x dwordx4 per WG, tag in low mantissa bits ----
    if (tid < 2) {
      const unsigned int tg = (t + 1) & 3u;
      uint32x4 pk;
      #pragma unroll
      for (int j = 0; j < 4; ++j)
        pk[j] = (__float_as_uint(stg[4 * tid + j]) & ~3u) | tg;
      uint32x4* dst = reinterpret_cast<uint32x4*>(swb) + wg * 2 + tid;
      asm volatile("global_store_dwordx4 %0, %1, off sc0 sc1"
                   :: "v"(dst), "v"(pk) : "memory");
    }
  }
}

// ---------------------------------------------------------------------------
// Kernel 3: out[t][o] = dot(states[t,:], rw[o,:]) + rb[o]
// ---------------------------------------------------------------------------
__global__ __launch_bounds__(256) void readout_kernel(
    const float* __restrict__ states, const float* __restrict__ rw,
    const float* __restrict__ rb, float* __restrict__ out) {
  const int t = blockIdx.x;
  const int tid = threadIdx.x;
  const int o = tid & 63;
  const int q = tid >> 6;  // 0..3
  __shared__ float ss[N_RES];
  #pragma unroll
  for (int k = 0; k < N_RES / 256; ++k)
    ss[tid + 256 * k] = states[(size_t)t * N_RES + tid + 256 * k];
  __syncthreads();

  const float4* r4 = reinterpret_cast<const float4*>(rw + (size_t)o * N_RES + q * 512);
  float acc = 0.f;
  #pragma unroll 8
  for (int j = 0; j < 128; ++j) {
    float4 w4 = r4[j];
    const int base = q * 512 + 4 * j;
    acc = fmaf(w4.x, ss[base + 0], acc);
    acc = fmaf(w4.y, ss[base + 1], acc);
    acc = fmaf(w4.z, ss[base + 2], acc);
    acc = fmaf(w4.w, ss[base + 3], acc);
  }
  __shared__ float red[256];
  red[tid] = acc;
  __syncthreads();
  if (tid < 64) {
    float v = red[tid] + red[tid + 64] + red[tid + 128] + red[tid + 192];
    out[(size_t)t * N_OUT + tid] = v + rb[tid];
  }
}

// ---------------------------------------------------------------------------
extern "C" void kernel_launch(void* const* d_in, const int* in_sizes, int n_in,
                              void* d_out, int out_size, void* d_ws, size_t ws_size,
                              hipStream_t stream) {
  const float* u     = (const float*)d_in[0];  // [4096, 64]
  const float* noise = (const float*)d_in[1];  // [4096, 2048]
  const float* W_in  = (const float*)d_in[2];  // [2048, 64]
  const float* W     = (const float*)d_in[3];  // [2048, 2048]
  const float* rw    = (const float*)d_in[4];  // [64, 2048]
  const float* rb    = (const float*)d_in[5];  // [64]
  float* out = (float*)d_out;                  // [4096, 64]

  float* it = (float*)d_ws;  // 32 MB: input terms, overwritten with states
  unsigned int* sbuf =
      (unsigned int*)((char*)d_ws + (size_t)T_STEPS * N_RES * sizeof(float));

  // Zero both tagged state buffers every call (tag 0 == initial zero state;
  // ws is not re-poisoned between replays). 2 * 2048 * 4B = 16 KB.
  hipMemsetAsync(sbuf, 0, 2 * N_RES * sizeof(unsigned int), stream);

  input_terms_kernel<<<T_STEPS, 256, 0, stream>>>(u, noise, W_in, it);

  void* args[] = {(void*)&W, (void*)&it, (void*)&sbuf};
  hipLaunchCooperativeKernel((void*)reservoir_kernel, dim3(256), dim3(256),
                             args, 0, stream);

  readout_kernel<<<T_STEPS, 256, 0, stream>>>(it, rw, rb, out);
}